// Round 7
// baseline (73.568 us; speedup 1.0000x reference)
//
#include <hip/hip_runtime.h>
#include <hip/hip_fp16.h>

#define BATCH 512
#define NI 8192
#define NO 8192
#define BT 64     // batch tile (pinned per XCD)
#define NBT 8     // number of batch tiles = XCDs
#define CTB 16    // columns per block
#define CAP 96    // padded bucket capacity per column (Poisson(32), P(>96) ~ 1e-19)

typedef float fx4 __attribute__((ext_vector_type(4)));

#if defined(__has_builtin)
#  if __has_builtin(__builtin_amdgcn_perm)
#    define WPAIR(p) __builtin_amdgcn_perm((p), (p), 0x03020302u)
#  endif
#endif
#ifndef WPAIR
#  define WPAIR(p) (((p) >> 16) | ((p) & 0xFFFF0000u))
#endif

__device__ __forceinline__ unsigned short f2h(float f) {
    return __half_as_ushort(__float2half_rn(f));
}

// ---- K1 (fused, interleaved): transpose x -> f16 xTt[bt][NI][64]  ||  hist+scatter edges ----

__global__ __launch_bounds__(256) void prep_kernel(const float* __restrict__ x,
                                                   unsigned short* __restrict__ xTt,
                                                   const int* __restrict__ row,
                                                   const int* __restrict__ col,
                                                   const float* __restrict__ w,
                                                   int* __restrict__ counts,
                                                   unsigned int* __restrict__ sedgeP,
                                                   int nnz, int sb) {
    __shared__ float tile[64][65];
    const int T = 1024;
    int id = blockIdx.x;
    int mn = T < sb ? T : sb;
    int role, sub;
    if (id < 2 * mn) { role = id & 1; sub = id >> 1; }
    else { sub = id - mn; role = (T > sb) ? 0 : 1; }

    if (role == 0) {
        int bx = sub & 127;            // input-dim tile
        int by = sub >> 7;             // batch tile (bt)
        int tx = threadIdx.x & 15;
        int ty = threadIdx.x >> 4;
#pragma unroll
        for (int k = 0; k < 4; ++k) {
            int b = by * 64 + ty + 16 * k;
            float4 v = *(const float4*)(x + (size_t)b * NI + bx * 64 + tx * 4);
            tile[ty + 16 * k][tx * 4 + 0] = v.x;
            tile[ty + 16 * k][tx * 4 + 1] = v.y;
            tile[ty + 16 * k][tx * 4 + 2] = v.z;
            tile[ty + 16 * k][tx * 4 + 3] = v.w;
        }
        __syncthreads();
#pragma unroll
        for (int k = 0; k < 4; ++k) {
            int rl = ty + 16 * k;
            int r = bx * 64 + rl;
            ushort4 v;
            v.x = f2h(tile[tx * 4 + 0][rl]);
            v.y = f2h(tile[tx * 4 + 1][rl]);
            v.z = f2h(tile[tx * 4 + 2][rl]);
            v.w = f2h(tile[tx * 4 + 3][rl]);
            *(ushort4*)(xTt + (size_t)by * NI * BT + (size_t)r * BT + tx * 4) = v;
        }
    } else {
        int e = sub * 256 + threadIdx.x;
        if (e < nnz) {
            int c = col[e];
            unsigned word = (unsigned)(row[e] & 0xFFFF) | ((unsigned)f2h(w[e]) << 16);
            int p = atomicAdd(&counts[c], 1);
            if (p < CAP) sedgeP[(size_t)c * CAP + p] = word;
        }
    }
}

// ---- K2: main gather/accumulate (pk_fma_f16, 8 gathers in flight per lane) ----

__global__ __launch_bounds__(256) void spmm_main_kernel(const unsigned short* __restrict__ xTt,
                                                        const unsigned int* __restrict__ sedgeP,
                                                        const int* __restrict__ counts,
                                                        const float* __restrict__ bias,
                                                        float* __restrict__ out) {
    __shared__ float tile[64 * 17];
    const int bt = blockIdx.x;               // 0..7 -> XCD via linear-id % 8
    const int wave = threadIdx.x >> 6;
    const int lane = threadIdx.x & 63;
    const int g = lane >> 4;                 // edge group 0..3
    const int i = lane & 15;                 // batch quad 0..15
    const int cb0 = blockIdx.y * CTB;
    const int c0 = cb0 + wave * 4;
    const char* xrow = (const char*)(xTt + (size_t)bt * NI * BT);
    const unsigned ib = (unsigned)(i * 8);   // byte offset of this lane's batch quad

    const __half2 hz = __float2half2_rn(0.f);
    float4 res[4];
#pragma unroll
    for (int cc = 0; cc < 4; ++cc) {
        int c = c0 + cc;
        int cnt = counts[c];
        cnt = cnt > CAP ? CAP : cnt;
        const unsigned int* eb = sedgeP + (size_t)c * CAP;
        __half2 accA[8], accB[8];
#pragma unroll
        for (int j = 0; j < 8; ++j) { accA[j] = hz; accB[j] = hz; }
        int e = g;
        // 32 edges per wave-round: 8 gathers in flight per lane
        for (; e + 28 < cnt; e += 32) {
            unsigned p[8];
            uint2 q[8];
#pragma unroll
            for (int j = 0; j < 8; ++j) p[j] = eb[e + 4 * j];
#pragma unroll
            for (int j = 0; j < 8; ++j)
                q[j] = *(const uint2*)(xrow + ((p[j] & 0xFFFFu) * 128u + ib));
#pragma unroll
            for (int j = 0; j < 8; ++j) {
                unsigned wp = WPAIR(p[j]);
                __half2 w2 = *reinterpret_cast<__half2*>(&wp);
                __half2 xa = *reinterpret_cast<__half2*>(&q[j].x);
                __half2 xc = *reinterpret_cast<__half2*>(&q[j].y);
                accA[j] = __hfma2(w2, xa, accA[j]);
                accB[j] = __hfma2(w2, xc, accB[j]);
            }
        }
        // 8-edge tier (2 per group)
        for (; e + 4 < cnt; e += 8) {
            unsigned p0 = eb[e], p1 = eb[e + 4];
            uint2 q0 = *(const uint2*)(xrow + ((p0 & 0xFFFFu) * 128u + ib));
            uint2 q1 = *(const uint2*)(xrow + ((p1 & 0xFFFFu) * 128u + ib));
            unsigned wp0 = WPAIR(p0), wp1 = WPAIR(p1);
            __half2 w0 = *reinterpret_cast<__half2*>(&wp0);
            __half2 w1 = *reinterpret_cast<__half2*>(&wp1);
            accA[0] = __hfma2(w0, *reinterpret_cast<__half2*>(&q0.x), accA[0]);
            accB[0] = __hfma2(w0, *reinterpret_cast<__half2*>(&q0.y), accB[0]);
            accA[1] = __hfma2(w1, *reinterpret_cast<__half2*>(&q1.x), accA[1]);
            accB[1] = __hfma2(w1, *reinterpret_cast<__half2*>(&q1.y), accB[1]);
        }
        if (e < cnt) {
            unsigned p = eb[e];
            uint2 q = *(const uint2*)(xrow + ((p & 0xFFFFu) * 128u + ib));
            unsigned wp = WPAIR(p);
            __half2 w2 = *reinterpret_cast<__half2*>(&wp);
            accA[2] = __hfma2(w2, *reinterpret_cast<__half2*>(&q.x), accA[2]);
            accB[2] = __hfma2(w2, *reinterpret_cast<__half2*>(&q.y), accB[2]);
        }
        // pairwise f16 tree, then f32
#pragma unroll
        for (int j = 0; j < 4; ++j) { accA[j] = __hadd2(accA[j], accA[j + 4]); accB[j] = __hadd2(accB[j], accB[j + 4]); }
#pragma unroll
        for (int j = 0; j < 2; ++j) { accA[j] = __hadd2(accA[j], accA[j + 2]); accB[j] = __hadd2(accB[j], accB[j + 2]); }
        accA[0] = __hadd2(accA[0], accA[1]);
        accB[0] = __hadd2(accB[0], accB[1]);
        float4 a0;
        a0.x = __low2float(accA[0]);
        a0.y = __high2float(accA[0]);
        a0.z = __low2float(accB[0]);
        a0.w = __high2float(accB[0]);
        // reduce over the 4 edge groups (lanes xor 16, 32) in f32
#pragma unroll
        for (int off = 16; off < 64; off <<= 1) {
            a0.x += __shfl_xor(a0.x, off, 64);
            a0.y += __shfl_xor(a0.y, off, 64);
            a0.z += __shfl_xor(a0.z, off, 64);
            a0.w += __shfl_xor(a0.w, off, 64);
        }
        res[cc] = a0;
    }

    // lane (i, g) owns column wave*4+g, batches i*4..+3 -> stage into LDS tile
    float4 r4 = (g == 0) ? res[0] : ((g == 1) ? res[1] : ((g == 2) ? res[2] : res[3]));
    int colL = wave * 4 + g;
    tile[(i * 4 + 0) * 17 + colL] = r4.x;
    tile[(i * 4 + 1) * 17 + colL] = r4.y;
    tile[(i * 4 + 2) * 17 + colL] = r4.z;
    tile[(i * 4 + 3) * 17 + colL] = r4.w;
    __syncthreads();

    // coalesced write-out
    int t = threadIdx.x;
    int r = t >> 2;
    int q = t & 3;
    float4 bb = *(const float4*)(bias + cb0 + q * 4);
    fx4 o;
    o.x = tile[r * 17 + q * 4 + 0] + bb.x;
    o.y = tile[r * 17 + q * 4 + 1] + bb.y;
    o.z = tile[r * 17 + q * 4 + 2] + bb.z;
    o.w = tile[r * 17 + q * 4 + 3] + bb.w;
    __builtin_nontemporal_store(o, (fx4*)(out + (size_t)(bt * BT + r) * NO + cb0 + q * 4));
}

// ---------------- launch ----------------

extern "C" void kernel_launch(void* const* d_in, const int* in_sizes, int n_in,
                              void* d_out, int out_size, void* d_ws, size_t ws_size,
                              hipStream_t stream) {
    const float* x    = (const float*)d_in[0];
    const float* w    = (const float*)d_in[1];
    const float* bias = (const float*)d_in[2];
    const int*   row  = (const int*)d_in[3];
    const int*   col  = (const int*)d_in[4];
    float* out = (float*)d_out;
    int nnz = in_sizes[1];

    char* ws = (char*)d_ws;
    size_t off = 0;
    unsigned short* xTt = (unsigned short*)(ws + off);
    off += (size_t)NI * BATCH * sizeof(unsigned short);            // 8 MB
    unsigned int* sedgeP = (unsigned int*)(ws + off);
    off += (size_t)NO * CAP * sizeof(unsigned int);                // 3 MB
    int* counts = (int*)(ws + off);
    off += (size_t)NO * sizeof(int);

    (void)hipMemsetAsync(counts, 0, (size_t)NO * sizeof(int), stream);
    int sb = (nnz + 255) / 256;    // 1 edge per thread
    prep_kernel<<<1024 + sb, 256, 0, stream>>>(x, xTt, row, col, w, counts, sedgeP, nnz, sb);
    spmm_main_kernel<<<dim3(NBT, NO / CTB), 256, 0, stream>>>(xTt, sedgeP, counts, bias, out);
}

// Round 8
// 46.177 us; speedup vs baseline: 1.5932x; 1.5932x over previous
//
#include <hip/hip_runtime.h>
#include <hip/hip_fp16.h>

#define BATCH 512
#define NI 8192
#define NO 8192
#define BT 64     // batch tile (pinned per XCD)
#define NBT 8     // number of batch tiles = XCDs
#define CTB 32    // columns per block (4 waves x 8 cols)
#define CAP 96    // padded bucket capacity per column (Poisson(32), P(>96) ~ 1e-19)

typedef float fx4 __attribute__((ext_vector_type(4)));

#if defined(__has_builtin)
#  if __has_builtin(__builtin_amdgcn_perm)
#    define WPAIR(p) __builtin_amdgcn_perm((p), (p), 0x03020302u)
#  endif
#endif
#ifndef WPAIR
#  define WPAIR(p) (((p) >> 16) | ((p) & 0xFFFF0000u))
#endif

__device__ __forceinline__ unsigned short f2h(float f) {
    return __half_as_ushort(__float2half_rn(f));
}

// ---- K1 (fused): blocks [0, sb) hist+scatter edges; blocks [sb, sb+1024) transpose ----

__global__ __launch_bounds__(256) void prep_kernel(const float* __restrict__ x,
                                                   unsigned short* __restrict__ xTt,
                                                   const int* __restrict__ row,
                                                   const int* __restrict__ col,
                                                   const float* __restrict__ w,
                                                   int* __restrict__ counts,
                                                   unsigned int* __restrict__ sedgeP,
                                                   int nnz, int sb) {
    __shared__ float tile[64][65];
    int id = blockIdx.x;
    if (id < sb) {
        int e = (id * 256 + threadIdx.x) * 4;
        if (e + 3 < nnz) {
            int4 r = *(const int4*)(row + e);
            int4 c = *(const int4*)(col + e);
            float4 ww = *(const float4*)(w + e);
            int p;
            p = atomicAdd(&counts[c.x], 1);
            if (p < CAP) sedgeP[(size_t)c.x * CAP + p] = (unsigned)(r.x & 0xFFFF) | ((unsigned)f2h(ww.x) << 16);
            p = atomicAdd(&counts[c.y], 1);
            if (p < CAP) sedgeP[(size_t)c.y * CAP + p] = (unsigned)(r.y & 0xFFFF) | ((unsigned)f2h(ww.y) << 16);
            p = atomicAdd(&counts[c.z], 1);
            if (p < CAP) sedgeP[(size_t)c.z * CAP + p] = (unsigned)(r.z & 0xFFFF) | ((unsigned)f2h(ww.z) << 16);
            p = atomicAdd(&counts[c.w], 1);
            if (p < CAP) sedgeP[(size_t)c.w * CAP + p] = (unsigned)(r.w & 0xFFFF) | ((unsigned)f2h(ww.w) << 16);
        } else {
            for (; e < nnz; ++e) {
                int c = col[e];
                int p = atomicAdd(&counts[c], 1);
                if (p < CAP) sedgeP[(size_t)c * CAP + p] = (unsigned)(row[e] & 0xFFFF) | ((unsigned)f2h(w[e]) << 16);
            }
        }
    } else {
        int sub = id - sb;
        int bx = sub & 127;            // input-dim tile
        int by = sub >> 7;             // batch tile (bt)
        int tx = threadIdx.x & 15;
        int ty = threadIdx.x >> 4;
#pragma unroll
        for (int k = 0; k < 4; ++k) {
            int b = by * 64 + ty + 16 * k;
            float4 v = *(const float4*)(x + (size_t)b * NI + bx * 64 + tx * 4);
            tile[ty + 16 * k][tx * 4 + 0] = v.x;
            tile[ty + 16 * k][tx * 4 + 1] = v.y;
            tile[ty + 16 * k][tx * 4 + 2] = v.z;
            tile[ty + 16 * k][tx * 4 + 3] = v.w;
        }
        __syncthreads();
#pragma unroll
        for (int k = 0; k < 4; ++k) {
            int rl = ty + 16 * k;
            int r = bx * 64 + rl;
            ushort4 v;
            v.x = f2h(tile[tx * 4 + 0][rl]);
            v.y = f2h(tile[tx * 4 + 1][rl]);
            v.z = f2h(tile[tx * 4 + 2][rl]);
            v.w = f2h(tile[tx * 4 + 3][rl]);
            *(ushort4*)(xTt + (size_t)by * NI * BT + (size_t)r * BT + tx * 4) = v;
        }
    }
}

// ---- K2: main. 8-lane group owns one column; lane owns 8 batch (uint4 gather);
//      software-pipelined edge words; no cross-lane reduction. ----

__global__ __launch_bounds__(256) void spmm_main_kernel(const unsigned short* __restrict__ xTt,
                                                        const unsigned int* __restrict__ sedgeP,
                                                        const int* __restrict__ counts,
                                                        const float* __restrict__ bias,
                                                        float* __restrict__ out) {
    __shared__ float tile[64 * 33];          // [batch 64][col 32] pad 33
    const int bt = blockIdx.x;               // 0..7 -> XCD via linear-id % 8
    const int wave = threadIdx.x >> 6;
    const int lane = threadIdx.x & 63;
    const int gg = lane >> 3;                // column group 0..7
    const int i = lane & 7;                  // batch octet 0..7
    const int cb0 = blockIdx.y * CTB;
    const int colL = wave * 8 + gg;
    const int c = cb0 + colL;
    const char* xrow = (const char*)(xTt + (size_t)bt * NI * BT);
    const unsigned ib16 = (unsigned)(i * 16);   // byte offset of this lane's 8 batch f16

    int cnt = counts[c];
    cnt = cnt > CAP ? CAP : cnt;
    const unsigned int* eb = sedgeP + (size_t)c * CAP;

    const __half2 hz = __float2half2_rn(0.f);
    __half2 acc[4][4];
#pragma unroll
    for (int j = 0; j < 4; ++j)
#pragma unroll
        for (int k = 0; k < 4; ++k) acc[j][k] = hz;

    unsigned pcur[4];
#pragma unroll
    for (int j = 0; j < 4; ++j) pcur[j] = eb[j];

    for (int e = 0; e < cnt; e += 4) {
        // prefetch next chunk's edge words (stay in flight across this chunk's gathers)
        unsigned pnext[4];
#pragma unroll
        for (int j = 0; j < 4; ++j) {
            int idx = e + 4 + j;
            idx = idx > CAP - 1 ? CAP - 1 : idx;
            pnext[j] = eb[idx];
        }
        unsigned wv[4];
        uint4 qv[4];
#pragma unroll
        for (int j = 0; j < 4; ++j) {
            unsigned word = (e + j < cnt) ? pcur[j] : 0u;   // masked pad: w=0 -> no contribution
            wv[j] = word;
            unsigned off = (word & 0x1FFFu) * 128u + ib16;
            qv[j] = *(const uint4*)(xrow + off);
        }
#pragma unroll
        for (int j = 0; j < 4; ++j) {
            unsigned wp = WPAIR(wv[j]);
            __half2 w2 = *reinterpret_cast<__half2*>(&wp);
            acc[j][0] = __hfma2(w2, *reinterpret_cast<const __half2*>(&qv[j].x), acc[j][0]);
            acc[j][1] = __hfma2(w2, *reinterpret_cast<const __half2*>(&qv[j].y), acc[j][1]);
            acc[j][2] = __hfma2(w2, *reinterpret_cast<const __half2*>(&qv[j].z), acc[j][2]);
            acc[j][3] = __hfma2(w2, *reinterpret_cast<const __half2*>(&qv[j].w), acc[j][3]);
        }
#pragma unroll
        for (int j = 0; j < 4; ++j) pcur[j] = pnext[j];
    }

    // in-register tree over the 4 depth sets, f16 -> f32
#pragma unroll
    for (int k = 0; k < 4; ++k)
        acc[0][k] = __hadd2(__hadd2(acc[0][k], acc[1][k]), __hadd2(acc[2][k], acc[3][k]));
    float2 f0 = __half22float2(acc[0][0]);
    float2 f1 = __half22float2(acc[0][1]);
    float2 f2 = __half22float2(acc[0][2]);
    float2 f3 = __half22float2(acc[0][3]);

    // stage: lane (gg,i) owns col colL, batches i*8..+7
    float* tb = tile + (i * 8) * 33 + colL;
    tb[0 * 33] = f0.x; tb[1 * 33] = f0.y;
    tb[2 * 33] = f1.x; tb[3 * 33] = f1.y;
    tb[4 * 33] = f2.x; tb[5 * 33] = f2.y;
    tb[6 * 33] = f3.x; tb[7 * 33] = f3.y;
    __syncthreads();

    // coalesced write-out: 512 float4 slots, 2 per thread
    int t = threadIdx.x;
#pragma unroll
    for (int s = 0; s < 2; ++s) {
        int idx = t + s * 256;
        int r = idx >> 3;
        int q = idx & 7;
        float4 bb = *(const float4*)(bias + cb0 + q * 4);
        fx4 o;
        o.x = tile[r * 33 + q * 4 + 0] + bb.x;
        o.y = tile[r * 33 + q * 4 + 1] + bb.y;
        o.z = tile[r * 33 + q * 4 + 2] + bb.z;
        o.w = tile[r * 33 + q * 4 + 3] + bb.w;
        __builtin_nontemporal_store(o, (fx4*)(out + (size_t)(bt * BT + r) * NO + cb0 + q * 4));
    }
}

// ---------------- launch ----------------

extern "C" void kernel_launch(void* const* d_in, const int* in_sizes, int n_in,
                              void* d_out, int out_size, void* d_ws, size_t ws_size,
                              hipStream_t stream) {
    const float* x    = (const float*)d_in[0];
    const float* w    = (const float*)d_in[1];
    const float* bias = (const float*)d_in[2];
    const int*   row  = (const int*)d_in[3];
    const int*   col  = (const int*)d_in[4];
    float* out = (float*)d_out;
    int nnz = in_sizes[1];

    char* ws = (char*)d_ws;
    size_t off = 0;
    unsigned short* xTt = (unsigned short*)(ws + off);
    off += (size_t)NI * BATCH * sizeof(unsigned short);            // 8 MB
    unsigned int* sedgeP = (unsigned int*)(ws + off);
    off += (size_t)NO * CAP * sizeof(unsigned int);                // 3 MB
    int* counts = (int*)(ws + off);
    off += (size_t)NO * sizeof(int);

    (void)hipMemsetAsync(counts, 0, (size_t)NO * sizeof(int), stream);
    int sb = (nnz / 4 + 255) / 256;   // 4 edges per thread
    prep_kernel<<<sb + 1024, 256, 0, stream>>>(x, xTt, row, col, w, counts, sedgeP, nnz, sb);
    spmm_main_kernel<<<dim3(NBT, NO / CTB), 256, 0, stream>>>(xTt, sedgeP, counts, bias, out);
}